// Round 4
// baseline (631.552 us; speedup 1.0000x reference)
//
#include <hip/hip_runtime.h>
#include <hip/hip_bf16.h>

#define NNODES 50000
#define NEDGES 800000
#define NHEAD 8

typedef __attribute__((ext_vector_type(8))) short short8v;
typedef __attribute__((ext_vector_type(4))) float f32x4;

union U8 { short8v v; unsigned short u[8]; };

__device__ inline unsigned short f2bf(float f) {
    unsigned int u = __float_as_uint(f);
    unsigned int r = (u + 0x7FFFu + ((u >> 16) & 1u)) >> 16;
    return (unsigned short)r;
}

// ---- prep: W[k][n] f32 -> Wt[n][k] bf16, for WQ,WK,WV,WE1 ----
__global__ void prep_weights(const float* __restrict__ WQ, const float* __restrict__ WK,
                             const float* __restrict__ WV, const float* __restrict__ WE1,
                             unsigned short* __restrict__ Wt) {
    int idx = blockIdx.x * 256 + threadIdx.x;
    if (idx >= 4 * 16384) return;
    int m = idx >> 14, r = idx & 16383;
    int k = r >> 7, n = r & 127;
    const float* W = (m == 0) ? WQ : (m == 1) ? WK : (m == 2) ? WV : WE1;
    Wt[m * 16384 + n * 128 + k] = f2bf(W[k * 128 + n]);
}

// swizzled LDS byte offset: row-major [rows][128 bf16] (256B rows), 16-slot XOR swizzle
__device__ inline int swz(int row, int byteInRow) {
    return row * 256 + (byteInRow ^ ((row & 15) << 4));
}

// stage one 128x128 bf16 (pre-transposed) weight into swizzled LDS, 256 threads
__device__ inline void stageW256(char* Wl, const unsigned short* __restrict__ Wtm, int t) {
    int row = t >> 1, half = t & 1;
    const unsigned short* src = Wtm + row * 128 + half * 64;
#pragma unroll
    for (int i = 0; i < 8; i++) {
        short8v v = *reinterpret_cast<const short8v*>(src + i * 8);
        *reinterpret_cast<short8v*>(Wl + swz(row, half * 128 + i * 16)) = v;
    }
}

// stage one 128x128 bf16 (pre-transposed) weight into swizzled LDS, 512 threads
__device__ inline void stageW512(char* Wl, const unsigned short* __restrict__ Wtm, int t) {
    int row = t >> 2, q = t & 3;
    const unsigned short* src = Wtm + row * 128 + q * 32;
#pragma unroll
    for (int i = 0; i < 4; i++) {
        short8v v = *reinterpret_cast<const short8v*>(src + i * 8);
        *reinterpret_cast<short8v*>(Wl + swz(row, q * 64 + i * 16)) = v;
    }
}

// load one A-fragment set (4 k-steps) for row `aptr`, lane k-group lg
__device__ inline void loadAfrag(const float* aptr, int lg, short8v* a, bool ok) {
#pragma unroll
    for (int kk = 0; kk < 4; kk++) {
        U8 h;
        if (ok) {
            float4 f0 = *reinterpret_cast<const float4*>(aptr + kk * 32 + lg * 8);
            float4 f1 = *reinterpret_cast<const float4*>(aptr + kk * 32 + lg * 8 + 4);
            h.u[0] = f2bf(f0.x); h.u[1] = f2bf(f0.y); h.u[2] = f2bf(f0.z); h.u[3] = f2bf(f0.w);
            h.u[4] = f2bf(f1.x); h.u[5] = f2bf(f1.y); h.u[6] = f2bf(f1.z); h.u[7] = f2bf(f1.w);
        } else {
#pragma unroll
            for (int j = 0; j < 8; j++) h.u[j] = 0;
        }
        a[kk] = h.v;
    }
}

// ---- proj: Q = x@WQ + bQ ; K = x@WK ; V = x@WV ----
__global__ __launch_bounds__(256, 4) void proj_qkv(const float* __restrict__ x,
                                                   const unsigned short* __restrict__ Wt,
                                                   const float* __restrict__ bQ,
                                                   float* __restrict__ Q, float* __restrict__ K,
                                                   float* __restrict__ V) {
    __shared__ __align__(16) char Wl[32768];
    int t = threadIdx.x;
    int nb = blockIdx.x * 64;
    int lane = t & 63, w = t >> 6;
    int lg = lane >> 4, lr = lane & 15;

    int arow = nb + w * 16 + lr;
    bool ok = arow < NNODES;
    short8v a[4];
    loadAfrag(x + (size_t)arow * 128, lg, a, ok);

    float bq[8];
#pragma unroll
    for (int n = 0; n < 8; n++) bq[n] = bQ[n * 16 + lr];

    for (int m = 0; m < 3; m++) {
        __syncthreads();
        stageW256(Wl, Wt + m * 16384, t);
        __syncthreads();

        f32x4 acc[8];
#pragma unroll
        for (int n = 0; n < 8; n++) acc[n] = (f32x4){0.f, 0.f, 0.f, 0.f};
#pragma unroll
        for (int kk = 0; kk < 4; kk++) {
#pragma unroll
            for (int n = 0; n < 8; n++) {
                short8v b = *reinterpret_cast<short8v*>(Wl + swz(n * 16 + lr, (kk * 32 + lg * 8) * 2));
                acc[n] = __builtin_amdgcn_mfma_f32_16x16x32_bf16(a[kk], b, acc[n], 0, 0, 0);
            }
        }
        float* out = (m == 0) ? Q : (m == 1) ? K : V;
#pragma unroll
        for (int n = 0; n < 8; n++) {
            int c = n * 16 + lr;
            float bias = (m == 0) ? bq[n] : 0.f;
#pragma unroll
            for (int r = 0; r < 4; r++) {
                int gr = nb + w * 16 + lg * 4 + r;
                if (gr < NNODES) out[(size_t)gr * 128 + c] = acc[n][r] + bias;
            }
        }
    }
}

// ---- edge pass 1: E GEMM + score_e = (E+bE)*K[src]*Q[dst], wE out, clamped head scores ----
// 512 threads = 8 waves, 128 edges per block
__global__ __launch_bounds__(512, 8) void edge_score(const float* __restrict__ EA,
                                                     const unsigned short* __restrict__ Wt,
                                                     const float* __restrict__ bE1,
                                                     const int* __restrict__ eidx,
                                                     const float* __restrict__ Q,
                                                     const float* __restrict__ K,
                                                     float* __restrict__ wE,
                                                     float* __restrict__ scoreH) {
    __shared__ __align__(16) char Wl[32768];
    __shared__ int srcL[128], dstL[128];
    int t = threadIdx.x;
    int eb = blockIdx.x * 128;
    int lane = t & 63, w = t >> 6;
    int lg = lane >> 4, lr = lane & 15;

    stageW512(Wl, Wt + 3 * 16384, t);
    if (t < 128) srcL[t] = eidx[eb + t];
    else if (t < 256) dstL[t - 128] = eidx[NEDGES + eb + t - 128];
    float be[8];
#pragma unroll
    for (int n = 0; n < 8; n++) be[n] = bE1[n * 16 + lr];

    int arow = eb + w * 16 + lr;  // always < NEDGES (grid exact)
    short8v a[4];
    loadAfrag(EA + (size_t)arow * 128, lg, a, true);

    __syncthreads();

    f32x4 acc[8];
#pragma unroll
    for (int n = 0; n < 8; n++) acc[n] = (f32x4){0.f, 0.f, 0.f, 0.f};
#pragma unroll
    for (int kk = 0; kk < 4; kk++) {
#pragma unroll
        for (int n = 0; n < 8; n++) {
            short8v b = *reinterpret_cast<short8v*>(Wl + swz(n * 16 + lr, (kk * 32 + lg * 8) * 2));
            acc[n] = __builtin_amdgcn_mfma_f32_16x16x32_bf16(a[kk], b, acc[n], 0, 0, 0);
        }
    }

#pragma unroll
    for (int r = 0; r < 4; r++) {
        int loc = w * 16 + lg * 4 + r;
        int e = eb + loc;
        int s = srcL[loc], d = dstL[loc];
#pragma unroll
        for (int n = 0; n < 8; n++) {
            int c = n * 16 + lr;
            float se = (acc[n][r] + be[n]) * K[(size_t)s * 128 + c] * Q[(size_t)d * 128 + c];
            wE[(size_t)e * 128 + c] = se;
            float sum = se;
            sum += __shfl_xor(sum, 1);
            sum += __shfl_xor(sum, 2);
            sum += __shfl_xor(sum, 4);
            sum += __shfl_xor(sum, 8);
            if (lr == 0) {
                float sh = fminf(fmaxf(sum * 0.25f, -5.f), 5.f);
                scoreH[(size_t)e * 8 + n] = sh;
            }
        }
    }
}

// ---- counting sort by dst ----
__global__ void hist_kernel(const int* __restrict__ eidx, int* __restrict__ histo) {
    int e = blockIdx.x * 256 + threadIdx.x;
    if (e >= NEDGES) return;
    atomicAdd(&histo[eidx[NEDGES + e]], 1);
}

// scanA: per-block (256-wide) sums
__global__ __launch_bounds__(256) void scanA(const int* __restrict__ histo, int* __restrict__ bsum) {
    __shared__ int l[4];
    int t = threadIdx.x;
    int idx = blockIdx.x * 256 + t;
    int v = (idx < NNODES) ? histo[idx] : 0;
#pragma unroll
    for (int off = 32; off; off >>= 1) v += __shfl_down(v, off);
    if ((t & 63) == 0) l[t >> 6] = v;
    __syncthreads();
    if (t == 0) bsum[blockIdx.x] = l[0] + l[1] + l[2] + l[3];
}

// scanB: exclusive scan of 196 block sums (single block)
__global__ __launch_bounds__(256) void scanB(const int* __restrict__ bsum, int* __restrict__ boff) {
    __shared__ int l[256];
    int t = threadIdx.x;
    int v = (t < 196) ? bsum[t] : 0;
    l[t] = v;
    __syncthreads();
    for (int off = 1; off < 256; off <<= 1) {
        int tmp = (t >= off) ? l[t - off] : 0;
        __syncthreads();
        l[t] += tmp;
        __syncthreads();
    }
    if (t < 196) boff[t] = l[t] - v;
}

// scanC: per-block exclusive scan + base offset -> start, cursor
__global__ __launch_bounds__(256) void scanC(const int* __restrict__ histo,
                                             const int* __restrict__ boff,
                                             int* __restrict__ start, int* __restrict__ cursor) {
    __shared__ int l[256];
    int t = threadIdx.x;
    int idx = blockIdx.x * 256 + t;
    int v = (idx < NNODES) ? histo[idx] : 0;
    l[t] = v;
    __syncthreads();
    for (int off = 1; off < 256; off <<= 1) {
        int tmp = (t >= off) ? l[t - off] : 0;
        __syncthreads();
        l[t] += tmp;
        __syncthreads();
    }
    int excl = l[t] - v + boff[blockIdx.x];
    if (idx <= NNODES) {
        start[idx] = excl;
        if (idx < NNODES) cursor[idx] = excl;
    }
}

__global__ void scatter_edges(const int* __restrict__ eidx, int* __restrict__ cursor,
                              int* __restrict__ sortedE) {
    int e = blockIdx.x * 256 + threadIdx.x;
    if (e >= NEDGES) return;
    int d = eidx[NEDGES + e];
    int pos = atomicAdd(&cursor[d], 1);
    sortedE[pos] = e;
}

// ---- per-node softmax + aggregation: one wave per dst node ----
__global__ __launch_bounds__(256) void aggregate_pernode(const int* __restrict__ sortedE,
                                                         const int* __restrict__ start,
                                                         const int* __restrict__ eidx,
                                                         const float* __restrict__ scoreH,
                                                         const float* __restrict__ V,
                                                         const float* __restrict__ wE,
                                                         float* __restrict__ wV) {
    __shared__ int eL[4][64];
    __shared__ int sL[4][64];
    __shared__ float aL[4][512];
    int n = blockIdx.x * 4 + (threadIdx.x >> 6);
    if (n >= NNODES) return;
    int w = threadIdx.x >> 6;
    int lane = threadIdx.x & 63;
    int c = lane * 2, hj = lane >> 3;
    int s0 = start[n], cnt = start[n + 1] - s0;

    float ax = 0.f, ay = 0.f;

    if (cnt <= 64) {
        bool act = lane < cnt;
        int e = 0, s = 0;
        float sc[8];
        if (act) {
            e = sortedE[s0 + lane];
            s = eidx[e];
            float4 p0 = *reinterpret_cast<const float4*>(scoreH + (size_t)e * 8);
            float4 p1 = *reinterpret_cast<const float4*>(scoreH + (size_t)e * 8 + 4);
            sc[0] = p0.x; sc[1] = p0.y; sc[2] = p0.z; sc[3] = p0.w;
            sc[4] = p1.x; sc[5] = p1.y; sc[6] = p1.z; sc[7] = p1.w;
        } else {
#pragma unroll
            for (int h = 0; h < 8; h++) sc[h] = -1e30f;
        }
        float m[8];
#pragma unroll
        for (int h = 0; h < 8; h++) m[h] = sc[h];
#pragma unroll
        for (int st = 1; st < 64; st <<= 1)
#pragma unroll
            for (int h = 0; h < 8; h++) m[h] = fmaxf(m[h], __shfl_xor(m[h], st));
        float ex[8], den[8];
#pragma unroll
        for (int h = 0; h < 8; h++) { ex[h] = act ? __expf(sc[h] - m[h]) : 0.f; den[h] = ex[h]; }
#pragma unroll
        for (int st = 1; st < 64; st <<= 1)
#pragma unroll
            for (int h = 0; h < 8; h++) den[h] += __shfl_xor(den[h], st);
        if (act) {
            eL[w][lane] = e;
            sL[w][lane] = s;
#pragma unroll
            for (int h = 0; h < 8; h++) aL[w][lane * 8 + h] = ex[h] / (den[h] + 1e-16f);
        }
        asm volatile("s_waitcnt lgkmcnt(0)" ::: "memory");
        __builtin_amdgcn_sched_barrier(0);
#pragma unroll 4
        for (int i = 0; i < cnt; i++) {
            int e2 = eL[w][i], s2 = sL[w][i];
            float al = aL[w][i * 8 + hj];
            float2 we = *reinterpret_cast<const float2*>(wE + (size_t)e2 * 128 + c);
            float2 vv = *reinterpret_cast<const float2*>(V + (size_t)s2 * 128 + c);
            ax += (vv.x + we.x) * al;
            ay += (vv.y + we.y) * al;
        }
    } else {
        // generic path (rare): chunked over 64-edge groups
        float m[8];
#pragma unroll
        for (int h = 0; h < 8; h++) m[h] = -1e30f;
        for (int cb = 0; cb < cnt; cb += 64) {
            bool act = cb + lane < cnt;
            if (act) {
                int e = sortedE[s0 + cb + lane];
                float4 p0 = *reinterpret_cast<const float4*>(scoreH + (size_t)e * 8);
                float4 p1 = *reinterpret_cast<const float4*>(scoreH + (size_t)e * 8 + 4);
                m[0] = fmaxf(m[0], p0.x); m[1] = fmaxf(m[1], p0.y);
                m[2] = fmaxf(m[2], p0.z); m[3] = fmaxf(m[3], p0.w);
                m[4] = fmaxf(m[4], p1.x); m[5] = fmaxf(m[5], p1.y);
                m[6] = fmaxf(m[6], p1.z); m[7] = fmaxf(m[7], p1.w);
            }
        }
#pragma unroll
        for (int st = 1; st < 64; st <<= 1)
#pragma unroll
            for (int h = 0; h < 8; h++) m[h] = fmaxf(m[h], __shfl_xor(m[h], st));
        float den[8];
#pragma unroll
        for (int h = 0; h < 8; h++) den[h] = 0.f;
        for (int cb = 0; cb < cnt; cb += 64) {
            bool act = cb + lane < cnt;
            float pl[8];
            if (act) {
                int e = sortedE[s0 + cb + lane];
                float4 p0 = *reinterpret_cast<const float4*>(scoreH + (size_t)e * 8);
                float4 p1 = *reinterpret_cast<const float4*>(scoreH + (size_t)e * 8 + 4);
                pl[0] = p0.x; pl[1] = p0.y; pl[2] = p0.z; pl[3] = p0.w;
                pl[4] = p1.x; pl[5] = p1.y; pl[6] = p1.z; pl[7] = p1.w;
#pragma unroll
                for (int h = 0; h < 8; h++) den[h] += __expf(pl[h] - m[h]);
            }
        }
#pragma unroll
        for (int st = 1; st < 64; st <<= 1)
#pragma unroll
            for (int h = 0; h < 8; h++) den[h] += __shfl_xor(den[h], st);
        float inv[8];
#pragma unroll
        for (int h = 0; h < 8; h++) inv[h] = 1.f / (den[h] + 1e-16f);
        for (int cb = 0; cb < cnt; cb += 64) {
            int ccnt = min(64, cnt - cb);
            bool act = lane < ccnt;
            asm volatile("s_waitcnt lgkmcnt(0)" ::: "memory");
            if (act) {
                int e = sortedE[s0 + cb + lane];
                int s = eidx[e];
                float4 p0 = *reinterpret_cast<const float4*>(scoreH + (size_t)e * 8);
                float4 p1 = *reinterpret_cast<const float4*>(scoreH + (size_t)e * 8 + 4);
                float pl[8] = {p0.x, p0.y, p0.z, p0.w, p1.x, p1.y, p1.z, p1.w};
                eL[w][lane] = e;
                sL[w][lane] = s;
#pragma unroll
                for (int h = 0; h < 8; h++) aL[w][lane * 8 + h] = __expf(pl[h] - m[h]) * inv[h];
            }
            asm volatile("s_waitcnt lgkmcnt(0)" ::: "memory");
            __builtin_amdgcn_sched_barrier(0);
#pragma unroll 4
            for (int i = 0; i < ccnt; i++) {
                int e2 = eL[w][i], s2 = sL[w][i];
                float al = aL[w][i * 8 + hj];
                float2 we = *reinterpret_cast<const float2*>(wE + (size_t)e2 * 128 + c);
                float2 vv = *reinterpret_cast<const float2*>(V + (size_t)s2 * 128 + c);
                ax += (vv.x + we.x) * al;
                ay += (vv.y + we.y) * al;
            }
        }
    }
    *reinterpret_cast<float2*>(wV + (size_t)n * 128 + c) = make_float2(ax, ay);
}

extern "C" void kernel_launch(void* const* d_in, const int* in_sizes, int n_in,
                              void* d_out, int out_size, void* d_ws, size_t ws_size,
                              hipStream_t stream) {
    const float* x    = (const float*)d_in[0];
    const float* ea   = (const float*)d_in[1];
    const int*   eidx = (const int*)d_in[2];
    const float* WQ   = (const float*)d_in[3];
    const float* bQ   = (const float*)d_in[4];
    const float* WK   = (const float*)d_in[5];
    const float* WV   = (const float*)d_in[6];
    const float* WE1  = (const float*)d_in[7];
    const float* bE1  = (const float*)d_in[8];

    float* wV = (float*)d_out;                           // [50000,128]
    float* wE = (float*)d_out + (size_t)NNODES * 128;    // [800000,128]

    float* Q      = (float*)d_ws;
    float* K      = Q + (size_t)NNODES * 128;
    float* V      = K + (size_t)NNODES * 128;
    float* scoreH = V + (size_t)NNODES * 128;            // [800000,8] clamped scores
    unsigned short* Wt = (unsigned short*)(scoreH + (size_t)NEDGES * 8); // 4x[128][128] bf16
    int* histo   = (int*)(Wt + 4 * 16384);               // 50176
    int* start   = histo + 50176;                        // 50177
    int* cursor  = start + 50177;                        // 50176
    int* sortedE = cursor + 50176;                       // 800000
    int* bsum    = sortedE + NEDGES;                     // 196
    int* boff    = bsum + 256;                           // 196

    hipMemsetAsync(histo, 0, (size_t)50176 * 4, stream);

    prep_weights<<<(4 * 16384 + 255) / 256, 256, 0, stream>>>(WQ, WK, WV, WE1, Wt);
    hist_kernel<<<(NEDGES + 255) / 256, 256, 0, stream>>>(eidx, histo);
    scanA<<<196, 256, 0, stream>>>(histo, bsum);
    scanB<<<1, 256, 0, stream>>>(bsum, boff);
    scanC<<<196, 256, 0, stream>>>(histo, boff, start, cursor);
    scatter_edges<<<(NEDGES + 255) / 256, 256, 0, stream>>>(eidx, cursor, sortedE);
    proj_qkv<<<(NNODES + 63) / 64, 256, 0, stream>>>(x, Wt, bQ, Q, K, V);
    edge_score<<<NEDGES / 128, 512, 0, stream>>>(ea, Wt, bE1, eidx, Q, K, wE, scoreH);
    aggregate_pernode<<<(NNODES + 3) / 4, 256, 0, stream>>>(sortedE, start, eidx, scoreH, V, wE, wV);
}

// Round 5
// 520.727 us; speedup vs baseline: 1.2128x; 1.2128x over previous
//
#include <hip/hip_runtime.h>
#include <hip/hip_bf16.h>

#define NNODES 50000
#define NEDGES 800000
#define NHEAD 8

typedef __attribute__((ext_vector_type(8))) short short8v;
typedef __attribute__((ext_vector_type(4))) float f32x4;

union U8 { short8v v; unsigned short u[8]; };

__device__ inline unsigned short f2bf(float f) {
    unsigned int u = __float_as_uint(f);
    unsigned int r = (u + 0x7FFFu + ((u >> 16) & 1u)) >> 16;
    return (unsigned short)r;
}
__device__ inline float bf2f(unsigned int u) {
    return __uint_as_float(u << 16);
}

// ---- prep: W[k][n] f32 -> Wt[n][k] bf16, for WQ,WK,WV,WE1 ----
__global__ void prep_weights(const float* __restrict__ WQ, const float* __restrict__ WK,
                             const float* __restrict__ WV, const float* __restrict__ WE1,
                             unsigned short* __restrict__ Wt) {
    int idx = blockIdx.x * 256 + threadIdx.x;
    if (idx >= 4 * 16384) return;
    int m = idx >> 14, r = idx & 16383;
    int k = r >> 7, n = r & 127;
    const float* W = (m == 0) ? WQ : (m == 1) ? WK : (m == 2) ? WV : WE1;
    Wt[m * 16384 + n * 128 + k] = f2bf(W[k * 128 + n]);
}

// swizzled LDS byte offset: row-major [rows][128 bf16] (256B rows), 16-slot XOR swizzle
__device__ inline int swz(int row, int byteInRow) {
    return row * 256 + (byteInRow ^ ((row & 15) << 4));
}

// stage one 128x128 bf16 (pre-transposed) weight into swizzled LDS, 256 threads
__device__ inline void stageW256(char* Wl, const unsigned short* __restrict__ Wtm, int t) {
    int row = t >> 1, half = t & 1;
    const unsigned short* src = Wtm + row * 128 + half * 64;
#pragma unroll
    for (int i = 0; i < 8; i++) {
        short8v v = *reinterpret_cast<const short8v*>(src + i * 8);
        *reinterpret_cast<short8v*>(Wl + swz(row, half * 128 + i * 16)) = v;
    }
}

// stage one 128x128 bf16 (pre-transposed) weight into swizzled LDS, 512 threads
__device__ inline void stageW512(char* Wl, const unsigned short* __restrict__ Wtm, int t) {
    int row = t >> 2, q = t & 3;
    const unsigned short* src = Wtm + row * 128 + q * 32;
#pragma unroll
    for (int i = 0; i < 4; i++) {
        short8v v = *reinterpret_cast<const short8v*>(src + i * 8);
        *reinterpret_cast<short8v*>(Wl + swz(row, q * 64 + i * 16)) = v;
    }
}

// load one A-fragment set (4 k-steps) for row `aptr`, lane k-group lg
__device__ inline void loadAfrag(const float* aptr, int lg, short8v* a, bool ok) {
#pragma unroll
    for (int kk = 0; kk < 4; kk++) {
        U8 h;
        if (ok) {
            float4 f0 = *reinterpret_cast<const float4*>(aptr + kk * 32 + lg * 8);
            float4 f1 = *reinterpret_cast<const float4*>(aptr + kk * 32 + lg * 8 + 4);
            h.u[0] = f2bf(f0.x); h.u[1] = f2bf(f0.y); h.u[2] = f2bf(f0.z); h.u[3] = f2bf(f0.w);
            h.u[4] = f2bf(f1.x); h.u[5] = f2bf(f1.y); h.u[6] = f2bf(f1.z); h.u[7] = f2bf(f1.w);
        } else {
#pragma unroll
            for (int j = 0; j < 8; j++) h.u[j] = 0;
        }
        a[kk] = h.v;
    }
}

// ---- proj: Q = x@WQ + bQ ; K = x@WK ; V = x@WV ----
__global__ __launch_bounds__(256, 4) void proj_qkv(const float* __restrict__ x,
                                                   const unsigned short* __restrict__ Wt,
                                                   const float* __restrict__ bQ,
                                                   float* __restrict__ Q, float* __restrict__ K,
                                                   float* __restrict__ V) {
    __shared__ __align__(16) char Wl[32768];
    int t = threadIdx.x;
    int nb = blockIdx.x * 64;
    int lane = t & 63, w = t >> 6;
    int lg = lane >> 4, lr = lane & 15;

    int arow = nb + w * 16 + lr;
    bool ok = arow < NNODES;
    short8v a[4];
    loadAfrag(x + (size_t)arow * 128, lg, a, ok);

    float bq[8];
#pragma unroll
    for (int n = 0; n < 8; n++) bq[n] = bQ[n * 16 + lr];

    for (int m = 0; m < 3; m++) {
        __syncthreads();
        stageW256(Wl, Wt + m * 16384, t);
        __syncthreads();

        f32x4 acc[8];
#pragma unroll
        for (int n = 0; n < 8; n++) acc[n] = (f32x4){0.f, 0.f, 0.f, 0.f};
#pragma unroll
        for (int kk = 0; kk < 4; kk++) {
#pragma unroll
            for (int n = 0; n < 8; n++) {
                short8v b = *reinterpret_cast<short8v*>(Wl + swz(n * 16 + lr, (kk * 32 + lg * 8) * 2));
                acc[n] = __builtin_amdgcn_mfma_f32_16x16x32_bf16(a[kk], b, acc[n], 0, 0, 0);
            }
        }
        float* out = (m == 0) ? Q : (m == 1) ? K : V;
#pragma unroll
        for (int n = 0; n < 8; n++) {
            int c = n * 16 + lr;
            float bias = (m == 0) ? bq[n] : 0.f;
#pragma unroll
            for (int r = 0; r < 4; r++) {
                int gr = nb + w * 16 + lg * 4 + r;
                if (gr < NNODES) out[(size_t)gr * 128 + c] = acc[n][r] + bias;
            }
        }
    }
}

// ---- edge pass 1: E GEMM -> E-tile in LDS (bf16) -> row-parallel gather epilogue ----
// 512 threads = 8 waves, 128 edges per block. Weight LDS is reused for the E tile.
__global__ __launch_bounds__(512, 6) void edge_score(const float* __restrict__ EA,
                                                     const unsigned short* __restrict__ Wt,
                                                     const float* __restrict__ bE1,
                                                     const int* __restrict__ eidx,
                                                     const float* __restrict__ Q,
                                                     const float* __restrict__ K,
                                                     float* __restrict__ wE,
                                                     float* __restrict__ scoreH) {
    __shared__ __align__(16) char Wl[32768];   // weights, then E tile (128x128 bf16)
    __shared__ int srcL[128], dstL[128];
    int t = threadIdx.x;
    int eb = blockIdx.x * 128;
    int lane = t & 63, w = t >> 6;
    int lg = lane >> 4, lr = lane & 15;

    stageW512(Wl, Wt + 3 * 16384, t);
    if (t < 128) srcL[t] = eidx[eb + t];
    else if (t < 256) dstL[t - 128] = eidx[NEDGES + eb + t - 128];
    float be[8];
#pragma unroll
    for (int n = 0; n < 8; n++) be[n] = bE1[n * 16 + lr];

    int arow = eb + w * 16 + lr;  // always < NEDGES (grid exact)
    short8v a[4];
    loadAfrag(EA + (size_t)arow * 128, lg, a, true);

    __syncthreads();

    f32x4 acc[8];
#pragma unroll
    for (int n = 0; n < 8; n++) acc[n] = (f32x4){0.f, 0.f, 0.f, 0.f};
#pragma unroll
    for (int kk = 0; kk < 4; kk++) {
#pragma unroll
        for (int n = 0; n < 8; n++) {
            short8v b = *reinterpret_cast<short8v*>(Wl + swz(n * 16 + lr, (kk * 32 + lg * 8) * 2));
            acc[n] = __builtin_amdgcn_mfma_f32_16x16x32_bf16(a[kk], b, acc[n], 0, 0, 0);
        }
    }

    __syncthreads();  // all waves done reading the weight tile

    // write E = acc + bias to LDS as bf16; wave w owns rows [w*16, w*16+16)
#pragma unroll
    for (int n = 0; n < 8; n++) {
#pragma unroll
        for (int r = 0; r < 4; r++) {
            int row = w * 16 + lg * 4 + r;
            *reinterpret_cast<unsigned short*>(Wl + swz(row, (n * 16 + lr) * 2)) =
                f2bf(acc[n][r] + be[n]);
        }
    }
    // no barrier: each wave reads back only its own rows

    // gather epilogue: 64 lanes span one edge row (2 cols/lane)
    int h = lane >> 3;  // head of this lane's columns
#pragma unroll 4
    for (int i = 0; i < 16; i++) {
        int loc = w * 16 + i;
        int e = eb + loc;
        int s = srcL[loc], d = dstL[loc];
        unsigned int ep = *reinterpret_cast<unsigned int*>(Wl + swz(loc, lane * 4));
        float e0 = bf2f(ep & 0xffffu);
        float e1 = bf2f(ep >> 16);
        float2 kv = *reinterpret_cast<const float2*>(K + (size_t)s * 128 + lane * 2);
        float2 qv = *reinterpret_cast<const float2*>(Q + (size_t)d * 128 + lane * 2);
        float s0 = e0 * kv.x * qv.x;
        float s1 = e1 * kv.y * qv.y;
        *reinterpret_cast<float2*>(wE + (size_t)e * 128 + lane * 2) = make_float2(s0, s1);
        float sum = s0 + s1;
        sum += __shfl_xor(sum, 1);
        sum += __shfl_xor(sum, 2);
        sum += __shfl_xor(sum, 4);
        if ((lane & 7) == 0) {
            float sh = fminf(fmaxf(sum * 0.25f, -5.f), 5.f);
            scoreH[(size_t)e * 8 + h] = sh;
        }
    }
}

// ---- counting sort by dst ----
__global__ void hist_kernel(const int* __restrict__ eidx, int* __restrict__ histo) {
    int e = blockIdx.x * 256 + threadIdx.x;
    if (e >= NEDGES) return;
    atomicAdd(&histo[eidx[NEDGES + e]], 1);
}

// scanA: per-block (256-wide) sums
__global__ __launch_bounds__(256) void scanA(const int* __restrict__ histo, int* __restrict__ bsum) {
    __shared__ int l[4];
    int t = threadIdx.x;
    int idx = blockIdx.x * 256 + t;
    int v = (idx < NNODES) ? histo[idx] : 0;
#pragma unroll
    for (int off = 32; off; off >>= 1) v += __shfl_down(v, off);
    if ((t & 63) == 0) l[t >> 6] = v;
    __syncthreads();
    if (t == 0) bsum[blockIdx.x] = l[0] + l[1] + l[2] + l[3];
}

// scanB: exclusive scan of 196 block sums (single block)
__global__ __launch_bounds__(256) void scanB(const int* __restrict__ bsum, int* __restrict__ boff) {
    __shared__ int l[256];
    int t = threadIdx.x;
    int v = (t < 196) ? bsum[t] : 0;
    l[t] = v;
    __syncthreads();
    for (int off = 1; off < 256; off <<= 1) {
        int tmp = (t >= off) ? l[t - off] : 0;
        __syncthreads();
        l[t] += tmp;
        __syncthreads();
    }
    if (t < 196) boff[t] = l[t] - v;
}

// scanC: per-block exclusive scan + base offset -> start, cursor
__global__ __launch_bounds__(256) void scanC(const int* __restrict__ histo,
                                             const int* __restrict__ boff,
                                             int* __restrict__ start, int* __restrict__ cursor) {
    __shared__ int l[256];
    int t = threadIdx.x;
    int idx = blockIdx.x * 256 + t;
    int v = (idx < NNODES) ? histo[idx] : 0;
    l[t] = v;
    __syncthreads();
    for (int off = 1; off < 256; off <<= 1) {
        int tmp = (t >= off) ? l[t - off] : 0;
        __syncthreads();
        l[t] += tmp;
        __syncthreads();
    }
    int excl = l[t] - v + boff[blockIdx.x];
    if (idx <= NNODES) {
        start[idx] = excl;
        if (idx < NNODES) cursor[idx] = excl;
    }
}

__global__ void scatter_edges(const int* __restrict__ eidx, int* __restrict__ cursor,
                              int* __restrict__ sortedE) {
    int e = blockIdx.x * 256 + threadIdx.x;
    if (e >= NEDGES) return;
    int d = eidx[NEDGES + e];
    int pos = atomicAdd(&cursor[d], 1);
    sortedE[pos] = e;
}

// ---- per-node softmax + aggregation: one wave per dst node ----
__global__ __launch_bounds__(256) void aggregate_pernode(const int* __restrict__ sortedE,
                                                         const int* __restrict__ start,
                                                         const int* __restrict__ eidx,
                                                         const float* __restrict__ scoreH,
                                                         const float* __restrict__ V,
                                                         const float* __restrict__ wE,
                                                         float* __restrict__ wV) {
    __shared__ int eL[4][64];
    __shared__ int sL[4][64];
    __shared__ float aL[4][512];
    int n = blockIdx.x * 4 + (threadIdx.x >> 6);
    if (n >= NNODES) return;
    int w = threadIdx.x >> 6;
    int lane = threadIdx.x & 63;
    int c = lane * 2, hj = lane >> 3;
    int s0 = start[n], cnt = start[n + 1] - s0;

    float ax = 0.f, ay = 0.f;

    if (cnt <= 64) {
        bool act = lane < cnt;
        int e = 0, s = 0;
        float sc[8];
        if (act) {
            e = sortedE[s0 + lane];
            s = eidx[e];
            float4 p0 = *reinterpret_cast<const float4*>(scoreH + (size_t)e * 8);
            float4 p1 = *reinterpret_cast<const float4*>(scoreH + (size_t)e * 8 + 4);
            sc[0] = p0.x; sc[1] = p0.y; sc[2] = p0.z; sc[3] = p0.w;
            sc[4] = p1.x; sc[5] = p1.y; sc[6] = p1.z; sc[7] = p1.w;
        } else {
#pragma unroll
            for (int h = 0; h < 8; h++) sc[h] = -1e30f;
        }
        float m[8];
#pragma unroll
        for (int h = 0; h < 8; h++) m[h] = sc[h];
#pragma unroll
        for (int st = 1; st < 64; st <<= 1)
#pragma unroll
            for (int h = 0; h < 8; h++) m[h] = fmaxf(m[h], __shfl_xor(m[h], st));
        float ex[8], den[8];
#pragma unroll
        for (int h = 0; h < 8; h++) { ex[h] = act ? __expf(sc[h] - m[h]) : 0.f; den[h] = ex[h]; }
#pragma unroll
        for (int st = 1; st < 64; st <<= 1)
#pragma unroll
            for (int h = 0; h < 8; h++) den[h] += __shfl_xor(den[h], st);
        if (act) {
            eL[w][lane] = e;
            sL[w][lane] = s;
#pragma unroll
            for (int h = 0; h < 8; h++) aL[w][lane * 8 + h] = ex[h] / (den[h] + 1e-16f);
        }
        asm volatile("s_waitcnt lgkmcnt(0)" ::: "memory");
        __builtin_amdgcn_sched_barrier(0);
#pragma unroll 4
        for (int i = 0; i < cnt; i++) {
            int e2 = eL[w][i], s2 = sL[w][i];
            float al = aL[w][i * 8 + hj];
            float2 we = *reinterpret_cast<const float2*>(wE + (size_t)e2 * 128 + c);
            float2 vv = *reinterpret_cast<const float2*>(V + (size_t)s2 * 128 + c);
            ax += (vv.x + we.x) * al;
            ay += (vv.y + we.y) * al;
        }
    } else {
        // generic path (rare): chunked over 64-edge groups
        float m[8];
#pragma unroll
        for (int h = 0; h < 8; h++) m[h] = -1e30f;
        for (int cb = 0; cb < cnt; cb += 64) {
            bool act = cb + lane < cnt;
            if (act) {
                int e = sortedE[s0 + cb + lane];
                float4 p0 = *reinterpret_cast<const float4*>(scoreH + (size_t)e * 8);
                float4 p1 = *reinterpret_cast<const float4*>(scoreH + (size_t)e * 8 + 4);
                m[0] = fmaxf(m[0], p0.x); m[1] = fmaxf(m[1], p0.y);
                m[2] = fmaxf(m[2], p0.z); m[3] = fmaxf(m[3], p0.w);
                m[4] = fmaxf(m[4], p1.x); m[5] = fmaxf(m[5], p1.y);
                m[6] = fmaxf(m[6], p1.z); m[7] = fmaxf(m[7], p1.w);
            }
        }
#pragma unroll
        for (int st = 1; st < 64; st <<= 1)
#pragma unroll
            for (int h = 0; h < 8; h++) m[h] = fmaxf(m[h], __shfl_xor(m[h], st));
        float den[8];
#pragma unroll
        for (int h = 0; h < 8; h++) den[h] = 0.f;
        for (int cb = 0; cb < cnt; cb += 64) {
            bool act = cb + lane < cnt;
            float pl[8];
            if (act) {
                int e = sortedE[s0 + cb + lane];
                float4 p0 = *reinterpret_cast<const float4*>(scoreH + (size_t)e * 8);
                float4 p1 = *reinterpret_cast<const float4*>(scoreH + (size_t)e * 8 + 4);
                pl[0] = p0.x; pl[1] = p0.y; pl[2] = p0.z; pl[3] = p0.w;
                pl[4] = p1.x; pl[5] = p1.y; pl[6] = p1.z; pl[7] = p1.w;
#pragma unroll
                for (int h = 0; h < 8; h++) den[h] += __expf(pl[h] - m[h]);
            }
        }
#pragma unroll
        for (int st = 1; st < 64; st <<= 1)
#pragma unroll
            for (int h = 0; h < 8; h++) den[h] += __shfl_xor(den[h], st);
        float inv[8];
#pragma unroll
        for (int h = 0; h < 8; h++) inv[h] = 1.f / (den[h] + 1e-16f);
        for (int cb = 0; cb < cnt; cb += 64) {
            int ccnt = min(64, cnt - cb);
            bool act = lane < ccnt;
            asm volatile("s_waitcnt lgkmcnt(0)" ::: "memory");
            if (act) {
                int e = sortedE[s0 + cb + lane];
                int s = eidx[e];
                float4 p0 = *reinterpret_cast<const float4*>(scoreH + (size_t)e * 8);
                float4 p1 = *reinterpret_cast<const float4*>(scoreH + (size_t)e * 8 + 4);
                float pl[8] = {p0.x, p0.y, p0.z, p0.w, p1.x, p1.y, p1.z, p1.w};
                eL[w][lane] = e;
                sL[w][lane] = s;
#pragma unroll
                for (int h = 0; h < 8; h++) aL[w][lane * 8 + h] = __expf(pl[h] - m[h]) * inv[h];
            }
            asm volatile("s_waitcnt lgkmcnt(0)" ::: "memory");
            __builtin_amdgcn_sched_barrier(0);
#pragma unroll 4
            for (int i = 0; i < ccnt; i++) {
                int e2 = eL[w][i], s2 = sL[w][i];
                float al = aL[w][i * 8 + hj];
                float2 we = *reinterpret_cast<const float2*>(wE + (size_t)e2 * 128 + c);
                float2 vv = *reinterpret_cast<const float2*>(V + (size_t)s2 * 128 + c);
                ax += (vv.x + we.x) * al;
                ay += (vv.y + we.y) * al;
            }
        }
    }
    *reinterpret_cast<float2*>(wV + (size_t)n * 128 + c) = make_float2(ax, ay);
}

extern "C" void kernel_launch(void* const* d_in, const int* in_sizes, int n_in,
                              void* d_out, int out_size, void* d_ws, size_t ws_size,
                              hipStream_t stream) {
    const float* x    = (const float*)d_in[0];
    const float* ea   = (const float*)d_in[1];
    const int*   eidx = (const int*)d_in[2];
    const float* WQ   = (const float*)d_in[3];
    const float* bQ   = (const float*)d_in[4];
    const float* WK   = (const float*)d_in[5];
    const float* WV   = (const float*)d_in[6];
    const float* WE1  = (const float*)d_in[7];
    const float* bE1  = (const float*)d_in[8];

    float* wV = (float*)d_out;                           // [50000,128]
    float* wE = (float*)d_out + (size_t)NNODES * 128;    // [800000,128]

    float* Q      = (float*)d_ws;
    float* K      = Q + (size_t)NNODES * 128;
    float* V      = K + (size_t)NNODES * 128;
    float* scoreH = V + (size_t)NNODES * 128;            // [800000,8] clamped scores
    unsigned short* Wt = (unsigned short*)(scoreH + (size_t)NEDGES * 8); // 4x[128][128] bf16
    int* histo   = (int*)(Wt + 4 * 16384);               // 50176
    int* start   = histo + 50176;                        // 50177
    int* cursor  = start + 50177;                        // 50176
    int* sortedE = cursor + 50176;                       // 800000
    int* bsum    = sortedE + NEDGES;                     // 196
    int* boff    = bsum + 256;                           // 196

    hipMemsetAsync(histo, 0, (size_t)50176 * 4, stream);

    prep_weights<<<(4 * 16384 + 255) / 256, 256, 0, stream>>>(WQ, WK, WV, WE1, Wt);
    hist_kernel<<<(NEDGES + 255) / 256, 256, 0, stream>>>(eidx, histo);
    scanA<<<196, 256, 0, stream>>>(histo, bsum);
    scanB<<<1, 256, 0, stream>>>(bsum, boff);
    scanC<<<196, 256, 0, stream>>>(histo, boff, start, cursor);
    scatter_edges<<<(NEDGES + 255) / 256, 256, 0, stream>>>(eidx, cursor, sortedE);
    proj_qkv<<<(NNODES + 63) / 64, 256, 0, stream>>>(x, Wt, bQ, Q, K, V);
    edge_score<<<NEDGES / 128, 512, 0, stream>>>(ea, Wt, bE1, eidx, Q, K, wE, scoreH);
    aggregate_pernode<<<(NNODES + 3) / 4, 256, 0, stream>>>(sortedE, start, eidx, scoreH, V, wE, wV);
}